// Round 2
// baseline (805.224 us; speedup 1.0000x reference)
//
#include <hip/hip_runtime.h>
#include <hip/hip_bf16.h>

typedef __attribute__((ext_vector_type(8))) short short8;
typedef __attribute__((ext_vector_type(4))) float f32x4;

#define DEVI static __device__ __forceinline__

DEVI ushort f2bf(float f) {
  union { __hip_bfloat16 h; ushort u; } c; c.h = __float2bfloat16(f); return c.u;
}
DEVI float bf2f(ushort u) {
  union { __hip_bfloat16 h; ushort u; } c; c.u = u; return __bfloat162float(c.h);
}

// async global->LDS, 16B per lane. LDS dest must be wave-uniform base + lane*16.
DEVI void gload16(const ushort* g, ushort* l) {
  __builtin_amdgcn_global_load_lds(
      (const __attribute__((address_space(1))) void*)g,
      (__attribute__((address_space(3))) void*)l, 16, 0, 0);
}

// block-wide (256 threads) reduction of two values
DEVI void blk_reduce2(float& a, float& b) {
  #pragma unroll
  for (int m = 1; m < 64; m <<= 1) {
    a += __shfl_xor(a, m);
    b += __shfl_xor(b, m);
  }
  __shared__ float sc[8];
  int tid = threadIdx.x, w = tid >> 6;
  if ((tid & 63) == 0) { sc[w * 2] = a; sc[w * 2 + 1] = b; }
  __syncthreads();
  if (tid == 0) {
    sc[0] = sc[0] + sc[2] + sc[4] + sc[6];
    sc[1] = sc[1] + sc[3] + sc[5] + sc[7];
  }
  __syncthreads();
  a = sc[0]; b = sc[1];
  __syncthreads();
}

// ---------------- weight transpose (f32 [k][n] -> bf16 [n][k]) + zero bstats ----
__global__ void kw_kernel(const float* w0, const float* w1, const float* w2, const float* w3,
                          ushort* wT, float* bstats) {
  int widx = blockIdx.y;
  const float* src = (widx == 0) ? w0 : (widx == 1) ? w1 : (widx == 2) ? w2 : w3;
  ushort* dst = wT + (size_t)widx * 65536;
  int tile = blockIdx.x;               // 0..15
  int k0 = (tile >> 2) * 64, n0 = (tile & 3) * 64;
  __shared__ float t[64][65];
  int tid = threadIdx.x;
  int r = tid >> 2, c0 = (tid & 3) * 16;
  #pragma unroll
  for (int j = 0; j < 16; j += 4) {
    float4 v = *reinterpret_cast<const float4*>(src + (size_t)(k0 + r) * 256 + n0 + c0 + j);
    t[r][c0 + j + 0] = v.x; t[r][c0 + j + 1] = v.y;
    t[r][c0 + j + 2] = v.z; t[r][c0 + j + 3] = v.w;
  }
  __syncthreads();
  ushort buf[16];
  #pragma unroll
  for (int j = 0; j < 16; j++) buf[j] = f2bf(t[c0 + j][r]);
  size_t o = (size_t)(n0 + r) * 256 + k0 + c0;
  *reinterpret_cast<uint4*>(dst + o) = *reinterpret_cast<uint4*>(&buf[0]);
  *reinterpret_cast<uint4*>(dst + o + 8) = *reinterpret_cast<uint4*>(&buf[8]);
  if (blockIdx.x == 0 && blockIdx.y == 0 && tid < 64) bstats[tid] = 0.f;
}

// ---------------- batch stats: sum, sumsq of h = x + pos over [D,NTOK] ---------
__global__ void k1_stats(const float* x, const float* pos_w, const float* pos_b, float* bstats) {
  int b = blockIdx.y, blk = blockIdx.x, tid = threadIdx.x;
  const float* xb = x + (size_t)b * 1048576;
  float s = 0.f, sq = 0.f;
  for (int i = 0; i < 16; i++) {
    int e4 = blk * 4096 + i * 256 + tid;   // float4 index within batch
    int e = e4 * 4;
    int d = e >> 12, t = e & 4095;
    int ii = t >> 6, j0 = t & 63;
    float xx = ii * (1.f / 63.f);
    float c0 = pos_w[512 + d] + pos_w[768 + d] + pos_b[d];
    float cx = pos_w[d] - pos_w[512 + d];
    float cy = pos_w[256 + d] - pos_w[768 + d];
    float4 v = reinterpret_cast<const float4*>(xb)[e4];
    float base = c0 + xx * cx;
    #pragma unroll
    for (int j = 0; j < 4; j++) {
      float yy = (j0 + j) * (1.f / 63.f);
      float h = (&v.x)[j] + base + yy * cy;
      s += h; sq += h * h;
    }
  }
  blk_reduce2(s, sq);
  if (tid == 0) {
    atomicAdd(&bstats[b * 2], s);
    atomicAdd(&bstats[b * 2 + 1], sq);
  }
}

// ---------------- tokens: transpose + batch-LN + enc affine -> bf16 [B*NTOK][D] -
__global__ void k2_tokens(const float* x, const float* pos_w, const float* pos_b,
                          const float* enc_g, const float* enc_b, const float* bstats,
                          ushort* t0) {
  int tcx = blockIdx.x;   // token row block 0..63
  int dcx = blockIdx.y;   // 0..3
  int b = blockIdx.z;
  int tid = threadIdx.x;
  float mean = bstats[b * 2] * (1.f / 1048576.f);
  float var = bstats[b * 2 + 1] * (1.f / 1048576.f) - mean * mean;
  float rstd = rsqrtf(var + 1e-5f);
  __shared__ float tt[64][65];          // [t_local][d_local]
  const float* xb = x + (size_t)b * 1048576;
  float xx = tcx * (1.f / 63.f);
  #pragma unroll
  for (int it = 0; it < 4; it++) {
    int idx = tid + it * 256;
    int dl = idx >> 4, f4 = idx & 15;
    int d = dcx * 64 + dl;
    float c0 = pos_w[512 + d] + pos_w[768 + d] + pos_b[d];
    float cx = pos_w[d] - pos_w[512 + d];
    float cy = pos_w[256 + d] - pos_w[768 + d];
    float4 v = *reinterpret_cast<const float4*>(xb + (size_t)d * 4096 + tcx * 64 + f4 * 4);
    float base = c0 + xx * cx;
    #pragma unroll
    for (int j = 0; j < 4; j++) {
      float yy = (f4 * 4 + j) * (1.f / 63.f);
      tt[f4 * 4 + j][dl] = (&v.x)[j] + base + yy * cy;
    }
  }
  __syncthreads();
  int t_l = tid >> 2, dc = (tid & 3) * 16;
  int t = tcx * 64 + t_l;
  ushort ob[16];
  #pragma unroll
  for (int j = 0; j < 16; j++) {
    int d = dcx * 64 + dc + j;
    float h = (tt[t_l][dc + j] - mean) * rstd;
    h = h * enc_g[(size_t)t * 256 + d] + enc_b[(size_t)t * 256 + d];
    ob[j] = f2bf(h);
  }
  size_t o = (size_t)(b * 4096 + t) * 256 + dcx * 64 + dc;
  *reinterpret_cast<uint4*>(t0 + o) = *reinterpret_cast<uint4*>(&ob[0]);
  *reinterpret_cast<uint4*>(t0 + o + 8) = *reinterpret_cast<uint4*>(&ob[8]);
}

// ---------------- GEMM: C = act(A @ W + bias) [, rowLN] --------------------------
// A row-major bf16 [M][256]; WT = W^T bf16 [256 n][256 k]. Block owns 128 full rows
// => in-place (C==A) is race-free. global_load_lds staging, linear LDS [r][64].
template <bool RELU, bool LN>
__global__ __launch_bounds__(512) void gemm_one(const ushort* __restrict__ A,
                                                const ushort* __restrict__ WT,
                                                const float* __restrict__ bias,
                                                const float* __restrict__ lng,
                                                const float* __restrict__ lnb,
                                                ushort* __restrict__ C) {
  __shared__ __align__(16) ushort As[128 * 64];
  __shared__ __align__(16) ushort Bs[256 * 64];
  __shared__ float rstats[128][4][2];
  int tid = threadIdx.x;
  int r0 = blockIdx.x * 128;
  int w = tid >> 6, lane = tid & 63;
  int wr = w >> 2, wc = w & 3;        // 2 x 4 waves, each 64(M) x 64(N)
  f32x4 acc[4][4];
  #pragma unroll
  for (int m = 0; m < 4; m++)
    #pragma unroll
    for (int n = 0; n < 4; n++) acc[m][n] = (f32x4)(0.f);

  for (int ks = 0; ks < 4; ks++) {
    int k0 = ks * 64;
    __syncthreads();
    #pragma unroll
    for (int i = 0; i < 2; i++) {     // A tile: 128 rows x 64 k
      int idx = tid + i * 512;
      gload16(A + (size_t)(r0 + (idx >> 3)) * 256 + k0 + (idx & 7) * 8, &As[idx * 8]);
    }
    #pragma unroll
    for (int i = 0; i < 4; i++) {     // B tile: 256 n-rows x 64 k
      int idx = tid + i * 512;
      gload16(WT + (size_t)(idx >> 3) * 256 + k0 + (idx & 7) * 8, &Bs[idx * 8]);
    }
    __syncthreads();
    #pragma unroll
    for (int ksub = 0; ksub < 2; ksub++) {
      int kk = ksub * 32 + (lane >> 4) * 8;
      short8 af[4], bf[4];
      #pragma unroll
      for (int m = 0; m < 4; m++)
        af[m] = *reinterpret_cast<const short8*>(&As[(wr * 64 + m * 16 + (lane & 15)) * 64 + kk]);
      #pragma unroll
      for (int n = 0; n < 4; n++)
        bf[n] = *reinterpret_cast<const short8*>(&Bs[(wc * 64 + n * 16 + (lane & 15)) * 64 + kk]);
      #pragma unroll
      for (int m = 0; m < 4; m++)
        #pragma unroll
        for (int n = 0; n < 4; n++)
          acc[m][n] = __builtin_amdgcn_mfma_f32_16x16x32_bf16(af[m], bf[n], acc[m][n], 0, 0, 0);
    }
  }
  // epilogue: bias [+relu] [+rowLN]
  float bcol[4], gcol[4], ocol[4];
  #pragma unroll
  for (int n = 0; n < 4; n++) {
    int col = wc * 64 + n * 16 + (lane & 15);
    bcol[n] = bias[col];
    if (LN) { gcol[n] = lng[col]; ocol[n] = lnb[col]; }
  }
  #pragma unroll
  for (int m = 0; m < 4; m++)
    #pragma unroll
    for (int n = 0; n < 4; n++)
      #pragma unroll
      for (int q = 0; q < 4; q++) {
        float v = acc[m][n][q] + bcol[n];
        if (RELU) v = fmaxf(v, 0.f);
        acc[m][n][q] = v;
      }
  if (LN) {
    #pragma unroll
    for (int m = 0; m < 4; m++)
      #pragma unroll
      for (int q = 0; q < 4; q++) {
        float rs = 0.f, rq = 0.f;
        #pragma unroll
        for (int n = 0; n < 4; n++) { float v = acc[m][n][q]; rs += v; rq += v * v; }
        #pragma unroll
        for (int msk = 1; msk < 16; msk <<= 1) { rs += __shfl_xor(rs, msk); rq += __shfl_xor(rq, msk); }
        if ((lane & 15) == 0) {
          int lr = wr * 64 + m * 16 + (lane >> 4) * 4 + q;
          rstats[lr][wc][0] = rs; rstats[lr][wc][1] = rq;
        }
      }
    __syncthreads();
    #pragma unroll
    for (int m = 0; m < 4; m++)
      #pragma unroll
      for (int q = 0; q < 4; q++) {
        int lr = wr * 64 + m * 16 + (lane >> 4) * 4 + q;
        float s = rstats[lr][0][0] + rstats[lr][1][0] + rstats[lr][2][0] + rstats[lr][3][0];
        float ssq = rstats[lr][0][1] + rstats[lr][1][1] + rstats[lr][2][1] + rstats[lr][3][1];
        float mean = s * (1.f / 256.f);
        float rstd = rsqrtf(ssq * (1.f / 256.f) - mean * mean + 1e-5f);
        #pragma unroll
        for (int n = 0; n < 4; n++)
          acc[m][n][q] = (acc[m][n][q] - mean) * rstd * gcol[n] + ocol[n];
      }
  }
  #pragma unroll
  for (int m = 0; m < 4; m++) {
    int row = r0 + wr * 64 + m * 16 + ((lane >> 4) << 2);
    #pragma unroll
    for (int n = 0; n < 4; n++) {
      int col = wc * 64 + n * 16 + (lane & 15);
      #pragma unroll
      for (int q = 0; q < 4; q++)
        C[(size_t)(row + q) * 256 + col] = f2bf(acc[m][n][q]);
    }
  }
}

// ---------------- dual GEMM: k = A@Wk+bk -> Ck; v = A@Wv+bv -> Cv (=A, in place) --
__global__ __launch_bounds__(512) void gemm_kv(const ushort* __restrict__ A,
                                               const ushort* __restrict__ WTk,
                                               const ushort* __restrict__ WTv,
                                               const float* __restrict__ bk,
                                               const float* __restrict__ bv,
                                               ushort* __restrict__ Ck,
                                               ushort* __restrict__ Cv) {
  __shared__ __align__(16) ushort As[128 * 64];
  __shared__ __align__(16) ushort Bs1[256 * 64];
  __shared__ __align__(16) ushort Bs2[256 * 64];
  int tid = threadIdx.x;
  int r0 = blockIdx.x * 128;
  int w = tid >> 6, lane = tid & 63;
  int wr = w >> 2, wc = w & 3;
  f32x4 acc1[4][4], acc2[4][4];
  #pragma unroll
  for (int m = 0; m < 4; m++)
    #pragma unroll
    for (int n = 0; n < 4; n++) { acc1[m][n] = (f32x4)(0.f); acc2[m][n] = (f32x4)(0.f); }

  for (int ks = 0; ks < 4; ks++) {
    int k0 = ks * 64;
    __syncthreads();
    #pragma unroll
    for (int i = 0; i < 2; i++) {
      int idx = tid + i * 512;
      gload16(A + (size_t)(r0 + (idx >> 3)) * 256 + k0 + (idx & 7) * 8, &As[idx * 8]);
    }
    #pragma unroll
    for (int i = 0; i < 4; i++) {
      int idx = tid + i * 512;
      gload16(WTk + (size_t)(idx >> 3) * 256 + k0 + (idx & 7) * 8, &Bs1[idx * 8]);
    }
    #pragma unroll
    for (int i = 0; i < 4; i++) {
      int idx = tid + i * 512;
      gload16(WTv + (size_t)(idx >> 3) * 256 + k0 + (idx & 7) * 8, &Bs2[idx * 8]);
    }
    __syncthreads();
    #pragma unroll
    for (int ksub = 0; ksub < 2; ksub++) {
      int kk = ksub * 32 + (lane >> 4) * 8;
      short8 af[4], bf1[4], bf2[4];
      #pragma unroll
      for (int m = 0; m < 4; m++)
        af[m] = *reinterpret_cast<const short8*>(&As[(wr * 64 + m * 16 + (lane & 15)) * 64 + kk]);
      #pragma unroll
      for (int n = 0; n < 4; n++) {
        bf1[n] = *reinterpret_cast<const short8*>(&Bs1[(wc * 64 + n * 16 + (lane & 15)) * 64 + kk]);
        bf2[n] = *reinterpret_cast<const short8*>(&Bs2[(wc * 64 + n * 16 + (lane & 15)) * 64 + kk]);
      }
      #pragma unroll
      for (int m = 0; m < 4; m++)
        #pragma unroll
        for (int n = 0; n < 4; n++) {
          acc1[m][n] = __builtin_amdgcn_mfma_f32_16x16x32_bf16(af[m], bf1[n], acc1[m][n], 0, 0, 0);
          acc2[m][n] = __builtin_amdgcn_mfma_f32_16x16x32_bf16(af[m], bf2[n], acc2[m][n], 0, 0, 0);
        }
    }
  }
  #pragma unroll
  for (int m = 0; m < 4; m++) {
    int row = r0 + wr * 64 + m * 16 + ((lane >> 4) << 2);
    #pragma unroll
    for (int n = 0; n < 4; n++) {
      int col = wc * 64 + n * 16 + (lane & 15);
      float b1 = bk[col], b2 = bv[col];
      #pragma unroll
      for (int q = 0; q < 4; q++) {
        Ck[(size_t)(row + q) * 256 + col] = f2bf(acc1[m][n][q] + b1);
        Cv[(size_t)(row + q) * 256 + col] = f2bf(acc2[m][n][q] + b2);
      }
    }
  }
}

// ---------------- slot init + slot-LN + q projection + zero upd/asum/q-pads -----
__global__ void kslots_q(const float* eps, const float* loc, const float* lsc,
                         const float* sg, const float* sb,
                         const float* qw, const float* qb,
                         float* slots, ushort* qT, float* upd, float* asum) {
  int s = blockIdx.x, b = blockIdx.y, tid = threadIdx.x;
  size_t base = ((size_t)b * 8 + s) * 256;
  float val = loc[tid] + expf(lsc[tid]) * eps[base + tid];
  slots[base + tid] = val;
  upd[base + tid] = 0.f;
  qT[((size_t)b * 16 + 8 + s) * 256 + tid] = 0;    // zero q padding row
  if (tid == 0) asum[b * 8 + s] = 0.f;
  __shared__ float sn[256];
  float a = val, sq = val * val;
  blk_reduce2(a, sq);
  float mean = a * (1.f / 256.f);
  float rstd = rsqrtf(sq * (1.f / 256.f) - mean * mean + 1e-5f);
  sn[tid] = (val - mean) * rstd * sg[tid] + sb[tid];
  __syncthreads();
  float qacc = qb[tid];
  for (int d = 0; d < 256; d++) qacc = fmaf(sn[d], qw[(size_t)d * 256 + tid], qacc);
  qT[((size_t)b * 16 + s) * 256 + tid] = f2bf(qacc * 0.0625f);   // fold SCALE
}

// ---------------- fused attention: dots(MFMA) + slot-softmax + attn@v -----------
__global__ __launch_bounds__(256) void kbc_kernel(const ushort* __restrict__ kmat,
                                                  const ushort* __restrict__ vmat,
                                                  const ushort* __restrict__ qT,
                                                  float* __restrict__ attn_sum,
                                                  float* __restrict__ upd) {
  int tcx = blockIdx.x;               // 0..15 (256 tokens each)
  int b = blockIdx.y;
  int tid = threadIdx.x, w = tid >> 6, lane = tid & 63;
  __shared__ __align__(16) ushort Ks[256 * 64];   // K staging; reused as `red` in PV
  __shared__ float at[256][9];                    // attn [token][slot], +1 pad
  __shared__ float wsum[4][16];
  const ushort* kbase = kmat + ((size_t)b * 4096 + tcx * 256) * 256;
  const ushort* qbase = qT + (size_t)b * 16 * 256;
  f32x4 acc[4];
  #pragma unroll
  for (int m = 0; m < 4; m++) acc[m] = (f32x4)(0.f);
  // phase 1: dots = K @ q^T
  for (int ks = 0; ks < 4; ks++) {
    int k0 = ks * 64;
    __syncthreads();
    #pragma unroll
    for (int i = 0; i < 8; i++) {
      int idx = tid + i * 256;
      gload16(kbase + (size_t)(idx >> 3) * 256 + k0 + (idx & 7) * 8, &Ks[idx * 8]);
    }
    __syncthreads();
    #pragma unroll
    for (int ksub = 0; ksub < 2; ksub++) {
      int kk = ksub * 32 + (lane >> 4) * 8;
      short8 bq = *reinterpret_cast<const short8*>(qbase + (lane & 15) * 256 + k0 + kk);
      #pragma unroll
      for (int m = 0; m < 4; m++) {
        short8 af = *reinterpret_cast<const short8*>(&Ks[(w * 64 + m * 16 + (lane & 15)) * 64 + kk]);
        acc[m] = __builtin_amdgcn_mfma_f32_16x16x32_bf16(af, bq, acc[m], 0, 0, 0);
      }
    }
  }
  // phase 2: softmax over slots (fragment cols) per token row -> at[][] + asum
  bool valid = (lane & 15) < 8;
  float lsum = 0.f;
  int srow = (lane >> 4) * 4;
  #pragma unroll
  for (int m = 0; m < 4; m++) {
    #pragma unroll
    for (int q = 0; q < 4; q++) {
      float d = acc[m][q];
      float mv = valid ? d : -1e30f;
      #pragma unroll
      for (int msk = 1; msk < 16; msk <<= 1) mv = fmaxf(mv, __shfl_xor(mv, msk));
      float e = valid ? expf(d - mv) : 0.f;
      float ssum = e;
      #pragma unroll
      for (int msk = 1; msk < 16; msk <<= 1) ssum += __shfl_xor(ssum, msk);
      if (valid) {
        float av = e / ssum + 1e-8f;
        int t = w * 64 + m * 16 + srow + q;
        at[t][lane & 15] = av;
        lsum += av;
      }
    }
  }
  lsum += __shfl_xor(lsum, 16);
  lsum += __shfl_xor(lsum, 32);
  if (lane < 16) wsum[w][lane] = lsum;
  __syncthreads();                     // at[] complete; Ks reads done -> reuse as red
  if (tid < 8) {
    float tot = wsum[0][tid] + wsum[1][tid] + wsum[2][tid] + wsum[3][tid];
    atomicAdd(&attn_sum[b * 8 + tid], tot);
  }
  // phase 3: upd partial = attn^T @ v; wave w handles tokens [w*64, w*64+64)
  float pacc[8][4];
  #pragma unroll
  for (int s = 0; s < 8; s++)
    #pragma unroll
    for (int j = 0; j < 4; j++) pacc[s][j] = 0.f;
  const ushort* vb = vmat + ((size_t)b * 4096 + tcx * 256) * 256;
  for (int ti = 0; ti < 64; ti++) {
    int t = w * 64 + ti;
    uint2 vv = *reinterpret_cast<const uint2*>(vb + (size_t)t * 256 + lane * 4);
    ushort us[4]; *reinterpret_cast<uint2*>(us) = vv;
    float vf[4];
    #pragma unroll
    for (int j = 0; j < 4; j++) vf[j] = bf2f(us[j]);
    #pragma unroll
    for (int s = 0; s < 8; s++) {
      float a = at[t][s];
      #pragma unroll
      for (int j = 0; j < 4; j++) pacc[s][j] = fmaf(a, vf[j], pacc[s][j]);
    }
  }
  float (*red)[8][256] = reinterpret_cast<float (*)[8][256]>(Ks);  // 32 KB overlay
  #pragma unroll
  for (int s = 0; s < 8; s++) {
    float4 v4; v4.x = pacc[s][0]; v4.y = pacc[s][1]; v4.z = pacc[s][2]; v4.w = pacc[s][3];
    *reinterpret_cast<float4*>(&red[w][s][lane * 4]) = v4;
  }
  __syncthreads();
  #pragma unroll
  for (int i = 0; i < 8; i++) {
    int idx = tid + i * 256;
    int s = idx >> 8, d = idx & 255;
    float sum = red[0][s][d] + red[1][s][d] + red[2][s][d] + red[3][s][d];
    atomicAdd(&upd[((size_t)b * 8 + s) * 256 + d], sum);
  }
}

// ---------------- GRU + residual MLP + (next-iter slot-LN+q, zero upd/asum) -----
__global__ void kd_kernel(const float* __restrict__ upd_in, const float* __restrict__ attn_sum,
                          float* __restrict__ slots,
                          const float* __restrict__ wih, const float* __restrict__ whh,
                          const float* __restrict__ bih, const float* __restrict__ bhh,
                          const float* __restrict__ pre_g, const float* __restrict__ pre_b,
                          const float* __restrict__ w1, const float* __restrict__ b1,
                          const float* __restrict__ w2, const float* __restrict__ b2,
                          const float* __restrict__ sg, const float* __restrict__ sb,
                          const float* __restrict__ qw, const float* __restrict__ qb,
                          ushort* __restrict__ qT_next, float* __restrict__ upd_clear,
                          float* __restrict__ asum_clear, float* __restrict__ out_final) {
  int s = blockIdx.x, b = blockIdx.y;
  int tid = threadIdx.x;
  size_t base = ((size_t)b * 8 + s) * 256;
  __shared__ float u[256], p[256], f1[256], f2[256];
  float inv = 1.f / attn_sum[b * 8 + s];
  u[tid] = upd_in[base + tid] * inv;
  p[tid] = slots[base + tid];
  __syncthreads();
  float gi0 = bih[tid], gi1 = bih[256 + tid], gi2 = bih[512 + tid];
  float gh0 = bhh[tid], gh1 = bhh[256 + tid], gh2 = bhh[512 + tid];
  #pragma unroll 4
  for (int d = 0; d < 256; d++) {
    float ud = u[d], pd = p[d];
    const float* wi = wih + (size_t)d * 768 + tid;
    const float* wh = whh + (size_t)d * 768 + tid;
    gi0 = fmaf(ud, wi[0], gi0); gi1 = fmaf(ud, wi[256], gi1); gi2 = fmaf(ud, wi[512], gi2);
    gh0 = fmaf(pd, wh[0], gh0); gh1 = fmaf(pd, wh[256], gh1); gh2 = fmaf(pd, wh[512], gh2);
  }
  float r = 1.f / (1.f + expf(-(gi0 + gh0)));
  float z = 1.f / (1.f + expf(-(gi1 + gh1)));
  float n = tanhf(gi2 + r * gh2);
  float hv = (1.f - z) * n + z * p[tid];
  float a = hv, sq = hv * hv;
  blk_reduce2(a, sq);
  float mean = a * (1.f / 256.f);
  float rstd = rsqrtf(sq * (1.f / 256.f) - mean * mean + 1e-5f);
  f1[tid] = (hv - mean) * rstd * pre_g[tid] + pre_b[tid];
  __syncthreads();
  float acc1 = b1[tid];
  #pragma unroll 4
  for (int d = 0; d < 256; d++) acc1 = fmaf(f1[d], w1[(size_t)d * 256 + tid], acc1);
  acc1 = fmaxf(acc1, 0.f);
  f2[tid] = acc1;
  __syncthreads();
  float acc2 = b2[tid];
  #pragma unroll 4
  for (int d = 0; d < 256; d++) acc2 = fmaf(f2[d], w2[(size_t)d * 256 + tid], acc2);
  acc2 = fmaxf(acc2, 0.f);
  float res = hv + acc2;
  slots[base + tid] = res;
  if (qT_next == nullptr) {
    out_final[base + tid] = res;
    return;
  }
  // next-iter: slot-LN + q projection
  float a2 = res, sq2 = res * res;
  blk_reduce2(a2, sq2);
  float mean2 = a2 * (1.f / 256.f);
  float rstd2 = rsqrtf(sq2 * (1.f / 256.f) - mean2 * mean2 + 1e-5f);
  f1[tid] = (res - mean2) * rstd2 * sg[tid] + sb[tid];
  __syncthreads();
  float qacc = qb[tid];
  #pragma unroll 4
  for (int d = 0; d < 256; d++) qacc = fmaf(f1[d], qw[(size_t)d * 256 + tid], qacc);
  qT_next[((size_t)b * 16 + s) * 256 + tid] = f2bf(qacc * 0.0625f);
  upd_clear[base + tid] = 0.f;
  if (tid == 0) asum_clear[b * 8 + s] = 0.f;
}

extern "C" void kernel_launch(void* const* d_in, const int* in_sizes, int n_in,
                              void* d_out, int out_size, void* d_ws, size_t ws_size,
                              hipStream_t stream) {
  const float* x         = (const float*)d_in[0];
  const float* eps_noise = (const float*)d_in[1];
  const float* pos_w     = (const float*)d_in[2];
  const float* pos_b     = (const float*)d_in[3];
  const float* enc_g     = (const float*)d_in[4];
  const float* enc_b     = (const float*)d_in[5];
  const float* fm_w1     = (const float*)d_in[6];
  const float* fm_b1     = (const float*)d_in[7];
  const float* fm_w2     = (const float*)d_in[8];
  const float* fm_b2     = (const float*)d_in[9];
  const float* in_g      = (const float*)d_in[10];
  const float* in_b      = (const float*)d_in[11];
  const float* q_w       = (const float*)d_in[12];
  const float* q_b       = (const float*)d_in[13];
  const float* k_w       = (const float*)d_in[14];
  const float* k_b       = (const float*)d_in[15];
  const float* v_w       = (const float*)d_in[16];
  const float* v_b       = (const float*)d_in[17];
  const float* gru_wih   = (const float*)d_in[18];
  const float* gru_whh   = (const float*)d_in[19];
  const float* gru_bih   = (const float*)d_in[20];
  const float* gru_bhh   = (const float*)d_in[21];
  const float* pre_g     = (const float*)d_in[22];
  const float* pre_b     = (const float*)d_in[23];
  const float* st_w1     = (const float*)d_in[24];
  const float* st_b1     = (const float*)d_in[25];
  const float* st_w2     = (const float*)d_in[26];
  const float* st_b2     = (const float*)d_in[27];
  const float* slot_g    = (const float*)d_in[28];
  const float* slot_b    = (const float*)d_in[29];
  const float* slots_loc = (const float*)d_in[30];
  const float* slots_lsc = (const float*)d_in[31];
  (void)in_sizes; (void)n_in; (void)out_size;

  char* ws = (char*)d_ws;
  const size_t OFF_BUFB   = 67108864;                 // bufA at 0 (64 MB)
  const size_t OFF_WT     = 134217728;                // 512 KB
  const size_t OFF_QT     = OFF_WT + 524288;          // 256 KB
  const size_t OFF_SLOTS  = OFF_QT + 262144;          // 256 KB
  const size_t OFF_UPD    = OFF_SLOTS + 262144;       // 256 KB
  const size_t OFF_BSTATS = OFF_UPD + 262144;         // 256 B
  const size_t OFF_ASUM   = OFF_BSTATS + 256;         // 1 KB
  const size_t NEED       = OFF_ASUM + 1024;
  if (ws_size < NEED) return;

  ushort* bufA   = (ushort*)ws;                       // tokens -> fm1 -> fm2+LN -> v
  ushort* bufB   = (ushort*)(ws + OFF_BUFB);          // k
  ushort* wT     = (ushort*)(ws + OFF_WT);
  ushort* qT     = (ushort*)(ws + OFF_QT);
  float* slots   = (float*)(ws + OFF_SLOTS);
  float* upd     = (float*)(ws + OFF_UPD);
  float* bstats  = (float*)(ws + OFF_BSTATS);
  float* asum    = (float*)(ws + OFF_ASUM);

  kw_kernel<<<dim3(16, 4), 256, 0, stream>>>(fm_w1, fm_w2, k_w, v_w, wT, bstats);
  k1_stats<<<dim3(64, 32), 256, 0, stream>>>(x, pos_w, pos_b, bstats);
  k2_tokens<<<dim3(64, 4, 32), 256, 0, stream>>>(x, pos_w, pos_b, enc_g, enc_b, bstats, bufA);
  gemm_one<true, false><<<1024, 512, 0, stream>>>(bufA, wT, fm_b1, nullptr, nullptr, bufA);
  gemm_one<true, true><<<1024, 512, 0, stream>>>(bufA, wT + 65536, fm_b2, in_g, in_b, bufA);
  gemm_kv<<<1024, 512, 0, stream>>>(bufA, wT + 131072, wT + 196608, k_b, v_b, bufB, bufA);
  kslots_q<<<dim3(8, 32), 256, 0, stream>>>(eps_noise, slots_loc, slots_lsc, slot_g, slot_b,
                                            q_w, q_b, slots, qT, upd, asum);
  for (int it = 0; it < 3; it++) {
    kbc_kernel<<<dim3(16, 32), 256, 0, stream>>>(bufB, bufA, qT, asum, upd);
    bool last = (it == 2);
    kd_kernel<<<dim3(8, 32), 256, 0, stream>>>(upd, asum, slots,
        gru_wih, gru_whh, gru_bih, gru_bhh, pre_g, pre_b,
        st_w1, st_b1, st_w2, st_b2, slot_g, slot_b, q_w, q_b,
        last ? nullptr : qT, upd, asum, last ? (float*)d_out : nullptr);
  }
}

// Round 3
// 622.179 us; speedup vs baseline: 1.2942x; 1.2942x over previous
//
#include <hip/hip_runtime.h>
#include <hip/hip_bf16.h>

typedef __attribute__((ext_vector_type(8))) short short8;
typedef __attribute__((ext_vector_type(4))) float f32x4;

#define DEVI static __device__ __forceinline__

DEVI ushort f2bf(float f) {
  union { __hip_bfloat16 h; ushort u; } c; c.h = __float2bfloat16(f); return c.u;
}
DEVI float bf2f(ushort u) {
  union { __hip_bfloat16 h; ushort u; } c; c.u = u; return __bfloat162float(c.h);
}

// async global->LDS, 16B per lane. LDS dest must be wave-uniform base + lane*16.
DEVI void gload16(const ushort* g, ushort* l) {
  __builtin_amdgcn_global_load_lds(
      (const __attribute__((address_space(1))) void*)g,
      (__attribute__((address_space(3))) void*)l, 16, 0, 0);
}

// block-wide (256 threads) reduction of two values
DEVI void blk_reduce2(float& a, float& b) {
  #pragma unroll
  for (int m = 1; m < 64; m <<= 1) {
    a += __shfl_xor(a, m);
    b += __shfl_xor(b, m);
  }
  __shared__ float sc[8];
  int tid = threadIdx.x, w = tid >> 6;
  if ((tid & 63) == 0) { sc[w * 2] = a; sc[w * 2 + 1] = b; }
  __syncthreads();
  if (tid == 0) {
    sc[0] = sc[0] + sc[2] + sc[4] + sc[6];
    sc[1] = sc[1] + sc[3] + sc[5] + sc[7];
  }
  __syncthreads();
  a = sc[0]; b = sc[1];
  __syncthreads();
}

// reduce (a,b) over the first 256 threads of a 1024-thread block.
// ALL threads must call (contains barriers). Result valid for every thread.
DEVI void red256_2(float& a, float& b, float* sc8) {
  int tid = threadIdx.x;
  #pragma unroll
  for (int m = 1; m < 64; m <<= 1) {
    a += __shfl_xor(a, m);
    b += __shfl_xor(b, m);
  }
  if (tid < 256 && (tid & 63) == 0) { sc8[(tid >> 6) * 2] = a; sc8[(tid >> 6) * 2 + 1] = b; }
  __syncthreads();
  a = sc8[0] + sc8[2] + sc8[4] + sc8[6];
  b = sc8[1] + sc8[3] + sc8[5] + sc8[7];
  __syncthreads();
}

// ---------------- weight transpose (f32 [k][n] -> bf16 [n][k]) + zero bstats ----
__global__ void kw_kernel(const float* w0, const float* w1, const float* w2, const float* w3,
                          ushort* wT, float* bstats) {
  int widx = blockIdx.y;
  const float* src = (widx == 0) ? w0 : (widx == 1) ? w1 : (widx == 2) ? w2 : w3;
  ushort* dst = wT + (size_t)widx * 65536;
  int tile = blockIdx.x;               // 0..15
  int k0 = (tile >> 2) * 64, n0 = (tile & 3) * 64;
  __shared__ float t[64][65];
  int tid = threadIdx.x;
  int r = tid >> 2, c0 = (tid & 3) * 16;
  #pragma unroll
  for (int j = 0; j < 16; j += 4) {
    float4 v = *reinterpret_cast<const float4*>(src + (size_t)(k0 + r) * 256 + n0 + c0 + j);
    t[r][c0 + j + 0] = v.x; t[r][c0 + j + 1] = v.y;
    t[r][c0 + j + 2] = v.z; t[r][c0 + j + 3] = v.w;
  }
  __syncthreads();
  ushort buf[16];
  #pragma unroll
  for (int j = 0; j < 16; j++) buf[j] = f2bf(t[c0 + j][r]);
  size_t o = (size_t)(n0 + r) * 256 + k0 + c0;
  *reinterpret_cast<uint4*>(dst + o) = *reinterpret_cast<uint4*>(&buf[0]);
  *reinterpret_cast<uint4*>(dst + o + 8) = *reinterpret_cast<uint4*>(&buf[8]);
  if (blockIdx.x == 0 && blockIdx.y == 0 && tid < 64) bstats[tid] = 0.f;
}

// ---------------- GRU/MLP/q weight prepack to bf16 ----------------------------
// grup[d][c][6] = {wih_r, wih_z, wih_n, whh_r, whh_z, whh_n} at (d, c)
__global__ void kw2_kernel(const float* wih, const float* whh, const float* w1,
                           const float* w2, const float* qw,
                           ushort* grup, ushort* w1b, ushort* w2b, ushort* qwb) {
  int d = blockIdx.x, c = threadIdx.x;
  ushort p6[6];
  p6[0] = f2bf(wih[(size_t)d * 768 + c]);
  p6[1] = f2bf(wih[(size_t)d * 768 + 256 + c]);
  p6[2] = f2bf(wih[(size_t)d * 768 + 512 + c]);
  p6[3] = f2bf(whh[(size_t)d * 768 + c]);
  p6[4] = f2bf(whh[(size_t)d * 768 + 256 + c]);
  p6[5] = f2bf(whh[(size_t)d * 768 + 512 + c]);
  size_t o = ((size_t)d * 256 + c) * 6;
  *reinterpret_cast<uint3*>(grup + o) = *reinterpret_cast<uint3*>(p6);
  int i = d * 256 + c;
  w1b[i] = f2bf(w1[i]);
  w2b[i] = f2bf(w2[i]);
  qwb[i] = f2bf(qw[i]);
}

// ---------------- batch stats: sum, sumsq of h = x + pos over [D,NTOK] ---------
__global__ void k1_stats(const float* x, const float* pos_w, const float* pos_b, float* bstats) {
  int b = blockIdx.y, blk = blockIdx.x, tid = threadIdx.x;
  const float* xb = x + (size_t)b * 1048576;
  float s = 0.f, sq = 0.f;
  for (int i = 0; i < 16; i++) {
    int e4 = blk * 4096 + i * 256 + tid;   // float4 index within batch
    int e = e4 * 4;
    int d = e >> 12, t = e & 4095;
    int ii = t >> 6, j0 = t & 63;
    float xx = ii * (1.f / 63.f);
    float c0 = pos_w[512 + d] + pos_w[768 + d] + pos_b[d];
    float cx = pos_w[d] - pos_w[512 + d];
    float cy = pos_w[256 + d] - pos_w[768 + d];
    float4 v = reinterpret_cast<const float4*>(xb)[e4];
    float base = c0 + xx * cx;
    #pragma unroll
    for (int j = 0; j < 4; j++) {
      float yy = (j0 + j) * (1.f / 63.f);
      float h = (&v.x)[j] + base + yy * cy;
      s += h; sq += h * h;
    }
  }
  blk_reduce2(s, sq);
  if (tid == 0) {
    atomicAdd(&bstats[b * 2], s);
    atomicAdd(&bstats[b * 2 + 1], sq);
  }
}

// ---------------- tokens: transpose + batch-LN + enc affine -> bf16 [B*NTOK][D] -
__global__ void k2_tokens(const float* x, const float* pos_w, const float* pos_b,
                          const float* enc_g, const float* enc_b, const float* bstats,
                          ushort* t0) {
  int tcx = blockIdx.x;   // token row block 0..63
  int dcx = blockIdx.y;   // 0..3
  int b = blockIdx.z;
  int tid = threadIdx.x;
  float mean = bstats[b * 2] * (1.f / 1048576.f);
  float var = bstats[b * 2 + 1] * (1.f / 1048576.f) - mean * mean;
  float rstd = rsqrtf(var + 1e-5f);
  __shared__ float tt[64][65];          // [t_local][d_local]
  const float* xb = x + (size_t)b * 1048576;
  float xx = tcx * (1.f / 63.f);
  #pragma unroll
  for (int it = 0; it < 4; it++) {
    int idx = tid + it * 256;
    int dl = idx >> 4, f4 = idx & 15;
    int d = dcx * 64 + dl;
    float c0 = pos_w[512 + d] + pos_w[768 + d] + pos_b[d];
    float cx = pos_w[d] - pos_w[512 + d];
    float cy = pos_w[256 + d] - pos_w[768 + d];
    float4 v = *reinterpret_cast<const float4*>(xb + (size_t)d * 4096 + tcx * 64 + f4 * 4);
    float base = c0 + xx * cx;
    #pragma unroll
    for (int j = 0; j < 4; j++) {
      float yy = (f4 * 4 + j) * (1.f / 63.f);
      tt[f4 * 4 + j][dl] = (&v.x)[j] + base + yy * cy;
    }
  }
  __syncthreads();
  int t_l = tid >> 2, dc = (tid & 3) * 16;
  int t = tcx * 64 + t_l;
  ushort ob[16];
  #pragma unroll
  for (int j = 0; j < 16; j++) {
    int d = dcx * 64 + dc + j;
    float h = (tt[t_l][dc + j] - mean) * rstd;
    h = h * enc_g[(size_t)t * 256 + d] + enc_b[(size_t)t * 256 + d];
    ob[j] = f2bf(h);
  }
  size_t o = (size_t)(b * 4096 + t) * 256 + dcx * 64 + dc;
  *reinterpret_cast<uint4*>(t0 + o) = *reinterpret_cast<uint4*>(&ob[0]);
  *reinterpret_cast<uint4*>(t0 + o + 8) = *reinterpret_cast<uint4*>(&ob[8]);
}

// ---------------- GEMM: C = act(A @ W + bias) [, rowLN] --------------------------
template <bool RELU, bool LN>
__global__ __launch_bounds__(512) void gemm_one(const ushort* __restrict__ A,
                                                const ushort* __restrict__ WT,
                                                const float* __restrict__ bias,
                                                const float* __restrict__ lng,
                                                const float* __restrict__ lnb,
                                                ushort* __restrict__ C) {
  __shared__ __align__(16) ushort As[128 * 64];
  __shared__ __align__(16) ushort Bs[256 * 64];
  __shared__ float rstats[128][4][2];
  int tid = threadIdx.x;
  int r0 = blockIdx.x * 128;
  int w = tid >> 6, lane = tid & 63;
  int wr = w >> 2, wc = w & 3;        // 2 x 4 waves, each 64(M) x 64(N)
  f32x4 acc[4][4];
  #pragma unroll
  for (int m = 0; m < 4; m++)
    #pragma unroll
    for (int n = 0; n < 4; n++) acc[m][n] = (f32x4)(0.f);

  for (int ks = 0; ks < 4; ks++) {
    int k0 = ks * 64;
    __syncthreads();
    #pragma unroll
    for (int i = 0; i < 2; i++) {     // A tile: 128 rows x 64 k
      int idx = tid + i * 512;
      gload16(A + (size_t)(r0 + (idx >> 3)) * 256 + k0 + (idx & 7) * 8, &As[idx * 8]);
    }
    #pragma unroll
    for (int i = 0; i < 4; i++) {     // B tile: 256 n-rows x 64 k
      int idx = tid + i * 512;
      gload16(WT + (size_t)(idx >> 3) * 256 + k0 + (idx & 7) * 8, &Bs[idx * 8]);
    }
    __syncthreads();
    #pragma unroll
    for (int ksub = 0; ksub < 2; ksub++) {
      int kk = ksub * 32 + (lane >> 4) * 8;
      short8 af[4], bf[4];
      #pragma unroll
      for (int m = 0; m < 4; m++)
        af[m] = *reinterpret_cast<const short8*>(&As[(wr * 64 + m * 16 + (lane & 15)) * 64 + kk]);
      #pragma unroll
      for (int n = 0; n < 4; n++)
        bf[n] = *reinterpret_cast<const short8*>(&Bs[(wc * 64 + n * 16 + (lane & 15)) * 64 + kk]);
      #pragma unroll
      for (int m = 0; m < 4; m++)
        #pragma unroll
        for (int n = 0; n < 4; n++)
          acc[m][n] = __builtin_amdgcn_mfma_f32_16x16x32_bf16(af[m], bf[n], acc[m][n], 0, 0, 0);
    }
  }
  float bcol[4], gcol[4], ocol[4];
  #pragma unroll
  for (int n = 0; n < 4; n++) {
    int col = wc * 64 + n * 16 + (lane & 15);
    bcol[n] = bias[col];
    if (LN) { gcol[n] = lng[col]; ocol[n] = lnb[col]; }
  }
  #pragma unroll
  for (int m = 0; m < 4; m++)
    #pragma unroll
    for (int n = 0; n < 4; n++)
      #pragma unroll
      for (int q = 0; q < 4; q++) {
        float v = acc[m][n][q] + bcol[n];
        if (RELU) v = fmaxf(v, 0.f);
        acc[m][n][q] = v;
      }
  if (LN) {
    #pragma unroll
    for (int m = 0; m < 4; m++)
      #pragma unroll
      for (int q = 0; q < 4; q++) {
        float rs = 0.f, rq = 0.f;
        #pragma unroll
        for (int n = 0; n < 4; n++) { float v = acc[m][n][q]; rs += v; rq += v * v; }
        #pragma unroll
        for (int msk = 1; msk < 16; msk <<= 1) { rs += __shfl_xor(rs, msk); rq += __shfl_xor(rq, msk); }
        if ((lane & 15) == 0) {
          int lr = wr * 64 + m * 16 + (lane >> 4) * 4 + q;
          rstats[lr][wc][0] = rs; rstats[lr][wc][1] = rq;
        }
      }
    __syncthreads();
    #pragma unroll
    for (int m = 0; m < 4; m++)
      #pragma unroll
      for (int q = 0; q < 4; q++) {
        int lr = wr * 64 + m * 16 + (lane >> 4) * 4 + q;
        float s = rstats[lr][0][0] + rstats[lr][1][0] + rstats[lr][2][0] + rstats[lr][3][0];
        float ssq = rstats[lr][0][1] + rstats[lr][1][1] + rstats[lr][2][1] + rstats[lr][3][1];
        float mean = s * (1.f / 256.f);
        float rstd = rsqrtf(ssq * (1.f / 256.f) - mean * mean + 1e-5f);
        #pragma unroll
        for (int n = 0; n < 4; n++)
          acc[m][n][q] = (acc[m][n][q] - mean) * rstd * gcol[n] + ocol[n];
      }
  }
  #pragma unroll
  for (int m = 0; m < 4; m++) {
    int row = r0 + wr * 64 + m * 16 + ((lane >> 4) << 2);
    #pragma unroll
    for (int n = 0; n < 4; n++) {
      int col = wc * 64 + n * 16 + (lane & 15);
      #pragma unroll
      for (int q = 0; q < 4; q++)
        C[(size_t)(row + q) * 256 + col] = f2bf(acc[m][n][q]);
    }
  }
}

// ---------------- dual GEMM: k = A@Wk+bk -> Ck; v = A@Wv+bv -> Cv (=A, in place) --
__global__ __launch_bounds__(512) void gemm_kv(const ushort* __restrict__ A,
                                               const ushort* __restrict__ WTk,
                                               const ushort* __restrict__ WTv,
                                               const float* __restrict__ bk,
                                               const float* __restrict__ bv,
                                               ushort* __restrict__ Ck,
                                               ushort* __restrict__ Cv) {
  __shared__ __align__(16) ushort As[128 * 64];
  __shared__ __align__(16) ushort Bs1[256 * 64];
  __shared__ __align__(16) ushort Bs2[256 * 64];
  int tid = threadIdx.x;
  int r0 = blockIdx.x * 128;
  int w = tid >> 6, lane = tid & 63;
  int wr = w >> 2, wc = w & 3;
  f32x4 acc1[4][4], acc2[4][4];
  #pragma unroll
  for (int m = 0; m < 4; m++)
    #pragma unroll
    for (int n = 0; n < 4; n++) { acc1[m][n] = (f32x4)(0.f); acc2[m][n] = (f32x4)(0.f); }

  for (int ks = 0; ks < 4; ks++) {
    int k0 = ks * 64;
    __syncthreads();
    #pragma unroll
    for (int i = 0; i < 2; i++) {
      int idx = tid + i * 512;
      gload16(A + (size_t)(r0 + (idx >> 3)) * 256 + k0 + (idx & 7) * 8, &As[idx * 8]);
    }
    #pragma unroll
    for (int i = 0; i < 4; i++) {
      int idx = tid + i * 512;
      gload16(WTk + (size_t)(idx >> 3) * 256 + k0 + (idx & 7) * 8, &Bs1[idx * 8]);
    }
    #pragma unroll
    for (int i = 0; i < 4; i++) {
      int idx = tid + i * 512;
      gload16(WTv + (size_t)(idx >> 3) * 256 + k0 + (idx & 7) * 8, &Bs2[idx * 8]);
    }
    __syncthreads();
    #pragma unroll
    for (int ksub = 0; ksub < 2; ksub++) {
      int kk = ksub * 32 + (lane >> 4) * 8;
      short8 af[4], bf1[4], bf2[4];
      #pragma unroll
      for (int m = 0; m < 4; m++)
        af[m] = *reinterpret_cast<const short8*>(&As[(wr * 64 + m * 16 + (lane & 15)) * 64 + kk]);
      #pragma unroll
      for (int n = 0; n < 4; n++) {
        bf1[n] = *reinterpret_cast<const short8*>(&Bs1[(wc * 64 + n * 16 + (lane & 15)) * 64 + kk]);
        bf2[n] = *reinterpret_cast<const short8*>(&Bs2[(wc * 64 + n * 16 + (lane & 15)) * 64 + kk]);
      }
      #pragma unroll
      for (int m = 0; m < 4; m++)
        #pragma unroll
        for (int n = 0; n < 4; n++) {
          acc1[m][n] = __builtin_amdgcn_mfma_f32_16x16x32_bf16(af[m], bf1[n], acc1[m][n], 0, 0, 0);
          acc2[m][n] = __builtin_amdgcn_mfma_f32_16x16x32_bf16(af[m], bf2[n], acc2[m][n], 0, 0, 0);
        }
    }
  }
  #pragma unroll
  for (int m = 0; m < 4; m++) {
    int row = r0 + wr * 64 + m * 16 + ((lane >> 4) << 2);
    #pragma unroll
    for (int n = 0; n < 4; n++) {
      int col = wc * 64 + n * 16 + (lane & 15);
      float b1 = bk[col], b2 = bv[col];
      #pragma unroll
      for (int q = 0; q < 4; q++) {
        Ck[(size_t)(row + q) * 256 + col] = f2bf(acc1[m][n][q] + b1);
        Cv[(size_t)(row + q) * 256 + col] = f2bf(acc2[m][n][q] + b2);
      }
    }
  }
}

// ---------------- slot init + slot-LN + q projection (K-split, 1024 thr) --------
__global__ __launch_bounds__(1024) void kslots_q(const float* eps, const float* loc,
                                                 const float* lsc, const float* sg,
                                                 const float* sb, const ushort* qwb,
                                                 const float* qb, float* slots, ushort* qT,
                                                 float* upd, float* asum) {
  int s = blockIdx.x, b = blockIdx.y, tid = threadIdx.x;
  int c = tid & 255, kq = tid >> 8;
  size_t base = ((size_t)b * 8 + s) * 256;
  __shared__ float sn[256];
  __shared__ float red[4][256];
  __shared__ float sc8[8];
  float val = 0.f;
  if (tid < 256) {
    val = loc[c] + expf(lsc[c]) * eps[base + c];
    slots[base + c] = val;
    upd[base + c] = 0.f;
    qT[((size_t)b * 16 + 8 + s) * 256 + c] = 0;   // zero q padding row
    if (tid == 0) asum[b * 8 + s] = 0.f;
  }
  float aa = val, bb = val * val;
  red256_2(aa, bb, sc8);
  if (tid < 256) {
    float mean = aa * (1.f / 256.f);
    float rstd = rsqrtf(bb * (1.f / 256.f) - mean * mean + 1e-5f);
    sn[c] = (val - mean) * rstd * sg[c] + sb[c];
  }
  __syncthreads();
  float qm = 0.f;
  const ushort* qp = qwb + (size_t)(kq * 64) * 256 + c;
  #pragma unroll 8
  for (int d0 = 0; d0 < 64; d0++) qm = fmaf(sn[kq * 64 + d0], bf2f(qp[(size_t)d0 * 256]), qm);
  red[kq][c] = qm;
  __syncthreads();
  if (tid < 256) {
    float qacc = qb[c] + red[0][c] + red[1][c] + red[2][c] + red[3][c];
    qT[((size_t)b * 16 + s) * 256 + c] = f2bf(qacc * 0.0625f);   // fold SCALE
  }
}

// ---------------- fused attention: dots(MFMA) + slot-softmax + attn@v -----------
__global__ __launch_bounds__(256) void kbc_kernel(const ushort* __restrict__ kmat,
                                                  const ushort* __restrict__ vmat,
                                                  const ushort* __restrict__ qT,
                                                  float* __restrict__ attn_sum,
                                                  float* __restrict__ upd) {
  int tcx = blockIdx.x;               // 0..15 (256 tokens each)
  int b = blockIdx.y;
  int tid = threadIdx.x, w = tid >> 6, lane = tid & 63;
  __shared__ __align__(16) ushort Ks[256 * 64];   // K staging; reused as `red` in PV
  __shared__ float at[256][9];                    // attn [token][slot], +1 pad
  __shared__ float wsum[4][16];
  const ushort* kbase = kmat + ((size_t)b * 4096 + tcx * 256) * 256;
  const ushort* qbase = qT + (size_t)b * 16 * 256;
  f32x4 acc[4];
  #pragma unroll
  for (int m = 0; m < 4; m++) acc[m] = (f32x4)(0.f);
  for (int ks = 0; ks < 4; ks++) {
    int k0 = ks * 64;
    __syncthreads();
    #pragma unroll
    for (int i = 0; i < 8; i++) {
      int idx = tid + i * 256;
      gload16(kbase + (size_t)(idx >> 3) * 256 + k0 + (idx & 7) * 8, &Ks[idx * 8]);
    }
    __syncthreads();
    #pragma unroll
    for (int ksub = 0; ksub < 2; ksub++) {
      int kk = ksub * 32 + (lane >> 4) * 8;
      short8 bq = *reinterpret_cast<const short8*>(qbase + (lane & 15) * 256 + k0 + kk);
      #pragma unroll
      for (int m = 0; m < 4; m++) {
        short8 af = *reinterpret_cast<const short8*>(&Ks[(w * 64 + m * 16 + (lane & 15)) * 64 + kk]);
        acc[m] = __builtin_amdgcn_mfma_f32_16x16x32_bf16(af, bq, acc[m], 0, 0, 0);
      }
    }
  }
  bool valid = (lane & 15) < 8;
  float lsum = 0.f;
  int srow = (lane >> 4) * 4;
  #pragma unroll
  for (int m = 0; m < 4; m++) {
    #pragma unroll
    for (int q = 0; q < 4; q++) {
      float d = acc[m][q];
      float mv = valid ? d : -1e30f;
      #pragma unroll
      for (int msk = 1; msk < 16; msk <<= 1) mv = fmaxf(mv, __shfl_xor(mv, msk));
      float e = valid ? expf(d - mv) : 0.f;
      float ssum = e;
      #pragma unroll
      for (int msk = 1; msk < 16; msk <<= 1) ssum += __shfl_xor(ssum, msk);
      if (valid) {
        float av = e / ssum + 1e-8f;
        int t = w * 64 + m * 16 + srow + q;
        at[t][lane & 15] = av;
        lsum += av;
      }
    }
  }
  lsum += __shfl_xor(lsum, 16);
  lsum += __shfl_xor(lsum, 32);
  if (lane < 16) wsum[w][lane] = lsum;
  __syncthreads();                     // at[] complete; Ks reads done -> reuse as red
  if (tid < 8) {
    float tot = wsum[0][tid] + wsum[1][tid] + wsum[2][tid] + wsum[3][tid];
    atomicAdd(&attn_sum[b * 8 + tid], tot);
  }
  float pacc[8][4];
  #pragma unroll
  for (int s = 0; s < 8; s++)
    #pragma unroll
    for (int j = 0; j < 4; j++) pacc[s][j] = 0.f;
  const ushort* vb = vmat + ((size_t)b * 4096 + tcx * 256) * 256;
  for (int ti = 0; ti < 64; ti++) {
    int t = w * 64 + ti;
    uint2 vv = *reinterpret_cast<const uint2*>(vb + (size_t)t * 256 + lane * 4);
    ushort us[4]; *reinterpret_cast<uint2*>(us) = vv;
    float vf[4];
    #pragma unroll
    for (int j = 0; j < 4; j++) vf[j] = bf2f(us[j]);
    #pragma unroll
    for (int s = 0; s < 8; s++) {
      float a = at[t][s];
      #pragma unroll
      for (int j = 0; j < 4; j++) pacc[s][j] = fmaf(a, vf[j], pacc[s][j]);
    }
  }
  float (*red)[8][256] = reinterpret_cast<float (*)[8][256]>(Ks);  // 32 KB overlay
  #pragma unroll
  for (int s = 0; s < 8; s++) {
    float4 v4; v4.x = pacc[s][0]; v4.y = pacc[s][1]; v4.z = pacc[s][2]; v4.w = pacc[s][3];
    *reinterpret_cast<float4*>(&red[w][s][lane * 4]) = v4;
  }
  __syncthreads();
  #pragma unroll
  for (int i = 0; i < 8; i++) {
    int idx = tid + i * 256;
    int s = idx >> 8, d = idx & 255;
    float sum = red[0][s][d] + red[1][s][d] + red[2][s][d] + red[3][s][d];
    atomicAdd(&upd[((size_t)b * 8 + s) * 256 + d], sum);
  }
}

// ---------------- GRU + residual MLP + next-iter q (K-split, 1024 thr) ---------
__global__ __launch_bounds__(1024) void kd_kernel(
    const float* __restrict__ upd_in, const float* __restrict__ attn_sum,
    float* __restrict__ slots, const ushort* __restrict__ grup,
    const float* __restrict__ bih, const float* __restrict__ bhh,
    const float* __restrict__ pre_g, const float* __restrict__ pre_b,
    const ushort* __restrict__ w1b, const float* __restrict__ b1,
    const ushort* __restrict__ w2b, const float* __restrict__ b2,
    const float* __restrict__ sg, const float* __restrict__ sb,
    const ushort* __restrict__ qwb, const float* __restrict__ qb,
    ushort* __restrict__ qT_next, float* __restrict__ upd_clear,
    float* __restrict__ asum_clear, float* __restrict__ out_final) {
  int s = blockIdx.x, b = blockIdx.y;
  int tid = threadIdx.x, c = tid & 255, kq = tid >> 8;
  size_t base = ((size_t)b * 8 + s) * 256;
  __shared__ float u[256], p[256], fbuf[256];
  __shared__ float red6[6][4][256];
  __shared__ float sc8[8];
  if (tid < 256) {
    u[c] = upd_in[base + c] * (1.f / attn_sum[b * 8 + s]);
    p[c] = slots[base + c];
  }
  __syncthreads();
  // GRU gates: 6 dot products over K=256, split 4 ways
  float a0 = 0.f, a1 = 0.f, a2 = 0.f, a3 = 0.f, a4 = 0.f, a5 = 0.f;
  const ushort* gp = grup + ((size_t)(kq * 64) * 256 + c) * 6;
  #pragma unroll 4
  for (int d0 = 0; d0 < 64; d0++) {
    int d = kq * 64 + d0;
    uint3 w3 = *reinterpret_cast<const uint3*>(gp + (size_t)d0 * 1536);
    float ud = u[d], pd = p[d];
    a0 = fmaf(ud, bf2f((ushort)(w3.x & 0xffff)), a0);
    a1 = fmaf(ud, bf2f((ushort)(w3.x >> 16)), a1);
    a2 = fmaf(ud, bf2f((ushort)(w3.y & 0xffff)), a2);
    a3 = fmaf(pd, bf2f((ushort)(w3.y >> 16)), a3);
    a4 = fmaf(pd, bf2f((ushort)(w3.z & 0xffff)), a4);
    a5 = fmaf(pd, bf2f((ushort)(w3.z >> 16)), a5);
  }
  red6[0][kq][c] = a0; red6[1][kq][c] = a1; red6[2][kq][c] = a2;
  red6[3][kq][c] = a3; red6[4][kq][c] = a4; red6[5][kq][c] = a5;
  __syncthreads();
  float hv = 0.f;
  if (tid < 256) {
    float gi0 = bih[c], gi1 = bih[256 + c], gi2 = bih[512 + c];
    float gh0 = bhh[c], gh1 = bhh[256 + c], gh2 = bhh[512 + c];
    #pragma unroll
    for (int k2 = 0; k2 < 4; k2++) {
      gi0 += red6[0][k2][c]; gi1 += red6[1][k2][c]; gi2 += red6[2][k2][c];
      gh0 += red6[3][k2][c]; gh1 += red6[4][k2][c]; gh2 += red6[5][k2][c];
    }
    float r = 1.f / (1.f + expf(-(gi0 + gh0)));
    float z = 1.f / (1.f + expf(-(gi1 + gh1)));
    float n = tanhf(gi2 + r * gh2);
    hv = (1.f - z) * n + z * p[c];
  }
  // LN(hv) -> fbuf
  float aa = hv, bb = hv * hv;
  red256_2(aa, bb, sc8);
  if (tid < 256) {
    float mean = aa * (1.f / 256.f);
    float rstd = rsqrtf(bb * (1.f / 256.f) - mean * mean + 1e-5f);
    fbuf[c] = (hv - mean) * rstd * pre_g[c] + pre_b[c];
  }
  __syncthreads();
  // MLP layer 1
  float m1 = 0.f;
  const ushort* w1p = w1b + (size_t)(kq * 64) * 256 + c;
  #pragma unroll 8
  for (int d0 = 0; d0 < 64; d0++) m1 = fmaf(fbuf[kq * 64 + d0], bf2f(w1p[(size_t)d0 * 256]), m1);
  red6[0][kq][c] = m1;
  __syncthreads();
  if (tid < 256) {
    float acc1 = b1[c] + red6[0][0][c] + red6[0][1][c] + red6[0][2][c] + red6[0][3][c];
    fbuf[c] = fmaxf(acc1, 0.f);
  }
  __syncthreads();
  // MLP layer 2
  float m2 = 0.f;
  const ushort* w2p = w2b + (size_t)(kq * 64) * 256 + c;
  #pragma unroll 8
  for (int d0 = 0; d0 < 64; d0++) m2 = fmaf(fbuf[kq * 64 + d0], bf2f(w2p[(size_t)d0 * 256]), m2);
  red6[1][kq][c] = m2;
  __syncthreads();
  float res = 0.f;
  if (tid < 256) {
    float acc2 = b2[c] + red6[1][0][c] + red6[1][1][c] + red6[1][2][c] + red6[1][3][c];
    res = hv + fmaxf(acc2, 0.f);
    slots[base + c] = res;
    if (qT_next == nullptr) out_final[base + c] = res;
  }
  if (qT_next != nullptr) {
    // next-iter: slot-LN + q projection
    float a2s = res, b2s = res * res;
    red256_2(a2s, b2s, sc8);
    if (tid < 256) {
      float mean2 = a2s * (1.f / 256.f);
      float rstd2 = rsqrtf(b2s * (1.f / 256.f) - mean2 * mean2 + 1e-5f);
      fbuf[c] = (res - mean2) * rstd2 * sg[c] + sb[c];
    }
    __syncthreads();
    float qm = 0.f;
    const ushort* qp = qwb + (size_t)(kq * 64) * 256 + c;
    #pragma unroll 8
    for (int d0 = 0; d0 < 64; d0++) qm = fmaf(fbuf[kq * 64 + d0], bf2f(qp[(size_t)d0 * 256]), qm);
    red6[2][kq][c] = qm;
    __syncthreads();
    if (tid < 256) {
      float qacc = qb[c] + red6[2][0][c] + red6[2][1][c] + red6[2][2][c] + red6[2][3][c];
      qT_next[((size_t)b * 16 + s) * 256 + c] = f2bf(qacc * 0.0625f);
      upd_clear[base + c] = 0.f;
      if (tid == 0) asum_clear[b * 8 + s] = 0.f;
    }
  }
}

extern "C" void kernel_launch(void* const* d_in, const int* in_sizes, int n_in,
                              void* d_out, int out_size, void* d_ws, size_t ws_size,
                              hipStream_t stream) {
  const float* x         = (const float*)d_in[0];
  const float* eps_noise = (const float*)d_in[1];
  const float* pos_w     = (const float*)d_in[2];
  const float* pos_b     = (const float*)d_in[3];
  const float* enc_g     = (const float*)d_in[4];
  const float* enc_b     = (const float*)d_in[5];
  const float* fm_w1     = (const float*)d_in[6];
  const float* fm_b1     = (const float*)d_in[7];
  const float* fm_w2     = (const float*)d_in[8];
  const float* fm_b2     = (const float*)d_in[9];
  const float* in_g      = (const float*)d_in[10];
  const float* in_b      = (const float*)d_in[11];
  const float* q_w       = (const float*)d_in[12];
  const float* q_b       = (const float*)d_in[13];
  const float* k_w       = (const float*)d_in[14];
  const float* k_b       = (const float*)d_in[15];
  const float* v_w       = (const float*)d_in[16];
  const float* v_b       = (const float*)d_in[17];
  const float* gru_wih   = (const float*)d_in[18];
  const float* gru_whh   = (const float*)d_in[19];
  const float* gru_bih   = (const float*)d_in[20];
  const float* gru_bhh   = (const float*)d_in[21];
  const float* pre_g     = (const float*)d_in[22];
  const float* pre_b     = (const float*)d_in[23];
  const float* st_w1     = (const float*)d_in[24];
  const float* st_b1     = (const float*)d_in[25];
  const float* st_w2     = (const float*)d_in[26];
  const float* st_b2     = (const float*)d_in[27];
  const float* slot_g    = (const float*)d_in[28];
  const float* slot_b    = (const float*)d_in[29];
  const float* slots_loc = (const float*)d_in[30];
  const float* slots_lsc = (const float*)d_in[31];
  (void)in_sizes; (void)n_in; (void)out_size;

  char* ws = (char*)d_ws;
  const size_t OFF_BUFB   = 67108864;                 // bufA at 0 (64 MB)
  const size_t OFF_WT     = 134217728;                // 512 KB
  const size_t OFF_QT     = OFF_WT + 524288;          // 256 KB
  const size_t OFF_SLOTS  = OFF_QT + 262144;          // 256 KB
  const size_t OFF_UPD    = OFF_SLOTS + 262144;       // 256 KB
  const size_t OFF_BSTATS = OFF_UPD + 262144;         // 256 B
  const size_t OFF_ASUM   = OFF_BSTATS + 256;         // 1 KB
  const size_t OFF_GRUP   = OFF_ASUM + 1024;          // 768 KB (bf16 packed GRU W)
  const size_t OFF_W1B    = OFF_GRUP + 786432;        // 128 KB
  const size_t OFF_W2B    = OFF_W1B + 131072;         // 128 KB
  const size_t OFF_QWB    = OFF_W2B + 131072;         // 128 KB
  const size_t NEED       = OFF_QWB + 131072;
  if (ws_size < NEED) return;

  ushort* bufA   = (ushort*)ws;                       // tokens -> fm1 -> fm2+LN -> v
  ushort* bufB   = (ushort*)(ws + OFF_BUFB);          // k
  ushort* wT     = (ushort*)(ws + OFF_WT);
  ushort* qT     = (ushort*)(ws + OFF_QT);
  float* slots   = (float*)(ws + OFF_SLOTS);
  float* upd     = (float*)(ws + OFF_UPD);
  float* bstats  = (float*)(ws + OFF_BSTATS);
  float* asum    = (float*)(ws + OFF_ASUM);
  ushort* grup   = (ushort*)(ws + OFF_GRUP);
  ushort* w1b    = (ushort*)(ws + OFF_W1B);
  ushort* w2b    = (ushort*)(ws + OFF_W2B);
  ushort* qwb    = (ushort*)(ws + OFF_QWB);

  kw_kernel<<<dim3(16, 4), 256, 0, stream>>>(fm_w1, fm_w2, k_w, v_w, wT, bstats);
  kw2_kernel<<<256, 256, 0, stream>>>(gru_wih, gru_whh, st_w1, st_w2, q_w,
                                      grup, w1b, w2b, qwb);
  k1_stats<<<dim3(64, 32), 256, 0, stream>>>(x, pos_w, pos_b, bstats);
  k2_tokens<<<dim3(64, 4, 32), 256, 0, stream>>>(x, pos_w, pos_b, enc_g, enc_b, bstats, bufA);
  gemm_one<true, false><<<1024, 512, 0, stream>>>(bufA, wT, fm_b1, nullptr, nullptr, bufA);
  gemm_one<true, true><<<1024, 512, 0, stream>>>(bufA, wT + 65536, fm_b2, in_g, in_b, bufA);
  gemm_kv<<<1024, 512, 0, stream>>>(bufA, wT + 131072, wT + 196608, k_b, v_b, bufB, bufA);
  kslots_q<<<dim3(8, 32), 1024, 0, stream>>>(eps_noise, slots_loc, slots_lsc, slot_g, slot_b,
                                             qwb, q_b, slots, qT, upd, asum);
  for (int it = 0; it < 3; it++) {
    kbc_kernel<<<dim3(16, 32), 256, 0, stream>>>(bufB, bufA, qT, asum, upd);
    bool last = (it == 2);
    kd_kernel<<<dim3(8, 32), 1024, 0, stream>>>(upd, asum, slots, grup,
        gru_bih, gru_bhh, pre_g, pre_b, w1b, st_b1, w2b, st_b2,
        slot_g, slot_b, qwb, q_b,
        last ? nullptr : qT, upd, asum, last ? (float*)d_out : nullptr);
  }
}